// Round 5
// baseline (1437.600 us; speedup 1.0000x reference)
//
#include <hip/hip_runtime.h>
#include <math.h>

#define NN 100000
#define NE 1600000
#define DD 32
#define CC 16
#define SCAN_B 391  // ceil(NN/256)

static inline unsigned gblocks(long total) { return (unsigned)((total + 255) / 256); }

__global__ void zero_int_k(int* p, int n) {
    int i = blockIdx.x * 256 + threadIdx.x;
    if (i < n) p[i] = 0;
}

__global__ void hist_k(const int* __restrict__ dst, int* __restrict__ cnt) {
    int e = blockIdx.x * 256 + threadIdx.x;
    if (e < NE) atomicAdd(&cnt[dst[e]], 1);
}

__global__ void s1_k(const int* __restrict__ cnt, int* __restrict__ offs,
                     int* __restrict__ bsum) {
    __shared__ int sm[256];
    int t = threadIdx.x, b = blockIdx.x;
    int g = b * 256 + t;
    int v = (g < NN) ? cnt[g] : 0;
    sm[t] = v;
    __syncthreads();
    for (int o = 1; o < 256; o <<= 1) {
        int u = (t >= o) ? sm[t - o] : 0;
        __syncthreads();
        sm[t] += u;
        __syncthreads();
    }
    if (g < NN) offs[g + 1] = sm[t];
    if (t == 255) bsum[b] = sm[255];
}

__global__ void s2_k(int* __restrict__ bsum) {
    __shared__ int sm[512];
    int t = threadIdx.x;
    int v = (t < SCAN_B) ? bsum[t] : 0;
    sm[t] = v;
    __syncthreads();
    for (int o = 1; o < 512; o <<= 1) {
        int u = (t >= o) ? sm[t - o] : 0;
        __syncthreads();
        sm[t] += u;
        __syncthreads();
    }
    if (t < SCAN_B) bsum[t] = sm[t] - v;  // exclusive
}

__global__ void s3_k(int* __restrict__ offs, const int* __restrict__ bsum) {
    int t = threadIdx.x, b = blockIdx.x;
    int g = b * 256 + t;
    if (g < NN) offs[g + 1] += bsum[b];
    if (g == 0) offs[0] = 0;
}

__global__ void copyoff_k(const int* __restrict__ offs, int* __restrict__ cur) {
    int g = blockIdx.x * 256 + threadIdx.x;
    if (g < NN) cur[g] = offs[g];
}

// CSR fill + pre-gather src/attr into dst-sorted order (coalesced edge streams later)
__global__ void fill_k(const int* __restrict__ dst, const int* __restrict__ src,
                       const float2* __restrict__ attr, int* __restrict__ cur,
                       int* __restrict__ esrc, float2* __restrict__ eattr) {
    int e = blockIdx.x * 256 + threadIdx.x;
    if (e < NE) {
        int pos = atomicAdd(&cur[dst[e]], 1);
        esrc[pos] = src[e];
        eattr[pos] = attr[e];
    }
}

// register z[k] tap-accumulate; kk is group-uniform; compile-time cases keep z in VGPRs
#define ZC(c) case c: if constexpr (c < K) z[c] = fmaf(b, xv, z[c]); break;
template<int K>
__device__ inline void zadd(float (&z)[K], int kk, float b, float xv) {
    switch (kk) {
        ZC(0) ZC(1) ZC(2) ZC(3) ZC(4) ZC(5) ZC(6) ZC(7) ZC(8)
        ZC(9) ZC(10) ZC(11) ZC(12) ZC(13) ZC(14) ZC(15) ZC(16)
        ZC(17) ZC(18) ZC(19) ZC(20) ZC(21) ZC(22) ZC(23) ZC(24)
        default: break;
    }
}

// Fused SplineConv layer: one 32-lane group per dst node (lane = feature dim).
// Phase 1: z[n,k,:] = sum_{e in(n)} b_{e,k} * x[src_e]  (z in registers)
// Phase 2: out = (sum_k z[k] @ W[k]) / deg + x[n] @ root + bias, ELU.
// W^T (+root) staged once per block in LDS, rows stride 34 (2-way bank = free).
template<int KS>
__global__ __launch_bounds__(512) void layer_k(
        const int* __restrict__ offs, const int* __restrict__ esrc,
        const float2* __restrict__ eattr, const float* __restrict__ xin,
        const float* __restrict__ W, const float* __restrict__ root,
        const float* __restrict__ bias, float* __restrict__ hout) {
    constexpr int K = KS * KS;
    __shared__ float Wl[(K + 1) * 32 * 34];
    __shared__ float zsl[16 * 32];

    // cooperative W^T load: Wl[(k*32+e)*34 + d] = W[k][d][e]; row K = root
    const int TOT = (K + 1) * 1024;
    for (int idx = threadIdx.x; idx < TOT; idx += 512) {
        int k = idx >> 10;
        int r = idx & 1023;
        int d = r >> 5;
        int e = r & 31;
        float v = (k < K) ? W[(k << 10) + (d << 5) + e] : root[(d << 5) + e];
        Wl[(k * 32 + e) * 34 + d] = v;
    }
    __syncthreads();

    const int lane = threadIdx.x & 31;
    const int grp = threadIdx.x >> 5;
    const int n = blockIdx.x * 16 + grp;
    if (n >= NN) return;

    const int j0 = offs[n], j1 = offs[n + 1];
    float z[K];
#pragma unroll
    for (int k = 0; k < K; ++k) z[k] = 0.f;

    for (int jb = j0; jb < j1; jb += 32) {
        int cn = j1 - jb; if (cn > 32) cn = 32;
        int sv = 0; float2 uv = make_float2(0.f, 0.f);
        if (lane < cn) { sv = esrc[jb + lane]; uv = eattr[jb + lane]; }
        for (int t = 0; t < cn; ++t) {
            int s = __shfl(sv, t, 32);
            float a0 = __shfl(uv.x, t, 32);
            float a1 = __shfl(uv.y, t, 32);
            float xv = xin[(long)s * DD + lane];   // 128B coalesced gather
            float v0 = a0 * (KS - 1), v1 = a1 * (KS - 1);
            float fb0 = floorf(v0), fb1 = floorf(v1);
            float f0 = v0 - fb0, f1 = v1 - fb1;
            int i0 = min((int)fb0, KS - 1), i1 = min((int)fb1, KS - 1);
            int q0 = min(i0 + 1, KS - 1), q1 = min(i1 + 1, KS - 1);
            float bx0 = 1.f - f0, by0 = 1.f - f1;
            zadd<K>(z, i0 + i1 * KS, bx0 * by0, xv);
            zadd<K>(z, q0 + i1 * KS, f0 * by0, xv);
            zadd<K>(z, i0 + q1 * KS, bx0 * f1, xv);
            zadd<K>(z, q0 + q1 * KS, f0 * f1, xv);
        }
    }

    // phase 2: contract z with W (z broadcast via per-group LDS slice; no barrier
    // needed -- a 32-lane group always lives in one wave, lockstep PC)
    float* zs = &zsl[grp * 32];
    const float* wb = Wl + lane * 34;
    float acc = 0.f;
#pragma unroll
    for (int k = 0; k < K; ++k) {
        zs[lane] = z[k];
        const float* wr = wb + k * (32 * 34);
#pragma unroll
        for (int d2 = 0; d2 < 16; ++d2) {
            float2 zz = *(const float2*)&zs[2 * d2];   // broadcast read
            float2 w  = *(const float2*)&wr[2 * d2];
            acc = fmaf(zz.x, w.x, acc);
            acc = fmaf(zz.y, w.y, acc);
        }
    }
    // root term
    float xv = xin[(long)n * DD + lane];
    zs[lane] = xv;
    {
        const float* wr = wb + K * (32 * 34);
        float racc = 0.f;
#pragma unroll
        for (int d2 = 0; d2 < 16; ++d2) {
            float2 zz = *(const float2*)&zs[2 * d2];
            float2 w  = *(const float2*)&wr[2 * d2];
            racc = fmaf(zz.x, w.x, racc);
            racc = fmaf(zz.y, w.y, racc);
        }
        int deg = j1 - j0;
        float dn = deg > 0 ? (float)deg : 1.f;
        float v = acc / dn + racc + bias[lane];
        hout[(long)n * DD + lane] = v > 0.f ? v : expm1f(v);
    }
}

// fused 2-layer MLP head: one 32-lane group per node
__global__ __launch_bounds__(256) void mlp_k(
        const float* __restrict__ h, const float* __restrict__ w1,
        const float* __restrict__ b1, const float* __restrict__ w2,
        const float* __restrict__ b2, float* __restrict__ out) {
    const int lane = threadIdx.x & 31;
    const int grp = threadIdx.x >> 5;
    const int n = blockIdx.x * 8 + grp;
    if (n >= NN) return;
    float hv = h[(long)n * DD + lane];
    float t = b1[lane];
#pragma unroll
    for (int d = 0; d < DD; ++d)
        t = fmaf(__shfl(hv, d, 32), w1[d * DD + lane], t);
    t = fmaxf(t, 0.f);
    int c = lane & (CC - 1);
    float o = 0.f;
#pragma unroll
    for (int d = 0; d < DD; ++d)
        o = fmaf(__shfl(t, d, 32), w2[d * CC + c], o);
    o += b2[c];
    o = fmaxf(o, 0.f);
    if (lane < CC) out[(long)n * CC + lane] = o;
}

extern "C" void kernel_launch(void* const* d_in, const int* in_sizes, int n_in,
                              void* d_out, int out_size, void* d_ws, size_t ws_size,
                              hipStream_t stream) {
    const float* x     = (const float*)d_in[0];
    const int*   ei    = (const int*)d_in[1];
    const float* attr  = (const float*)d_in[2];
    const float* W1    = (const float*)d_in[3];
    const float* root1 = (const float*)d_in[4];
    const float* bias1 = (const float*)d_in[5];
    const float* W2    = (const float*)d_in[6];
    const float* root2 = (const float*)d_in[7];
    const float* bias2 = (const float*)d_in[8];
    const float* m1w   = (const float*)d_in[9];
    const float* m1b   = (const float*)d_in[10];
    const float* m2w   = (const float*)d_in[11];
    const float* m2b   = (const float*)d_in[12];
    float* out = (float*)d_out;

    const int* srcp = ei;
    const int* dstp = ei + NE;

    // ws: offs(NN+2) | cur(NN) | bsum(512) | esrc(NE) | eattr(2*NE f32) | h1 | h2
    int* offs = (int*)d_ws;
    int* cur  = offs + NN + 2;
    int* bsum = cur + NN;
    int* esrc = bsum + 512;
    float2* eattr = (float2*)(esrc + NE);
    float* h1 = (float*)(esrc + NE + 2 * NE);
    float* h2 = h1 + (size_t)NN * DD;
    // total ~46 MB

    // ---- CSR build + edge pre-gather ----
    zero_int_k<<<gblocks(NN), 256, 0, stream>>>(cur, NN);
    hist_k<<<gblocks(NE), 256, 0, stream>>>(dstp, cur);
    s1_k<<<SCAN_B, 256, 0, stream>>>(cur, offs, bsum);
    s2_k<<<1, 512, 0, stream>>>(bsum);
    s3_k<<<SCAN_B, 256, 0, stream>>>(offs, bsum);
    copyoff_k<<<SCAN_B, 256, 0, stream>>>(offs, cur);
    fill_k<<<gblocks(NE), 256, 0, stream>>>(dstp, srcp, (const float2*)attr, cur, esrc, eattr);

    const unsigned gl = (NN + 15) / 16;
    const unsigned gn = (NN + 7) / 8;

    layer_k<3><<<gl, 512, 0, stream>>>(offs, esrc, eattr, x, W1, root1, bias1, h1);
    layer_k<5><<<gl, 512, 0, stream>>>(offs, esrc, eattr, h1, W2, root2, bias2, h2);
    mlp_k<<<gn, 256, 0, stream>>>(h2, m1w, m1b, m2w, m2b, out);
}